// Round 2
// baseline (6435.738 us; speedup 1.0000x reference)
//
#include <hip/hip_runtime.h>

typedef __bf16 bf16;
typedef __attribute__((ext_vector_type(8))) __bf16 bf16x8;
typedef __attribute__((ext_vector_type(4))) float f32x4;

#define NBASE  32768
#define NJOINT 98304
#define NFOOT  32768

static __device__ __forceinline__ f32x4 mfma16(bf16x8 a, bf16x8 b, f32x4 c) {
  return __builtin_amdgcn_mfma_f32_16x16x32_bf16(a, b, c, 0, 0, 0);
}

// ---------------- weight prep: fp32->bf16, Wroot/bias pre-summed per dst ----------------
__global__ __launch_bounds__(256) void prep_kernel(
    const float* __restrict__ Wrel, const float* __restrict__ Wroot,
    const float* __restrict__ brel, const float* __restrict__ bt1,
    const float* __restrict__ bt2,
    bf16* __restrict__ Wrel_b, bf16* __restrict__ Wroot_b,
    float* __restrict__ bias_s, bf16* __restrict__ bt1_b, bf16* __restrict__ bt2_b)
{
  int t = blockIdx.x * 256 + threadIdx.x;
  if (t < 4*8*16384) Wrel_b[t] = (bf16)Wrel[t];
  if (t < 4*3*16384) {
    int i = t & 16383; int ld = t >> 14; int l = ld / 3, dt = ld - l*3;
    const float* Wb = Wroot + l * 8 * 16384;
    float s;
    if (dt == 0)      s = Wb[0*16384+i] + Wb[1*16384+i] + Wb[2*16384+i] + Wb[4*16384+i];
    else if (dt == 1) s = Wb[3*16384+i] + Wb[5*16384+i] + Wb[7*16384+i];
    else              s = Wb[6*16384+i];
    Wroot_b[t] = (bf16)s;
  }
  if (t < 16384) { bt1_b[t] = (bf16)bt1[t]; bt2_b[t] = (bf16)bt2[t]; }
  if (t < 4*3*128) {
    int c = t & 127; int ld = t >> 7; int l = ld / 3, dt = ld - l*3;
    const float* B = brel + l * 8 * 128;
    float s;
    if (dt == 0)      s = B[0*128+c] + B[1*128+c] + B[2*128+c] + B[4*128+c];
    else if (dt == 1) s = B[3*128+c] + B[5*128+c] + B[7*128+c];
    else              s = B[6*128+c];
    bias_s[t] = s;
  }
}

// ---------------- degrees for mean-aggr edge types ----------------
__global__ __launch_bounds__(256) void zero_kernel(int* cnt) {
  cnt[blockIdx.x * 256 + threadIdx.x] = 0;
}
__global__ __launch_bounds__(256) void hist_kernel(const int* __restrict__ dgt,
                                                   const int* __restrict__ dgs,
                                                   int* __restrict__ cnt) {
  int t = blockIdx.x * 256 + threadIdx.x;
  if (t < 32768) atomicAdd(&cnt[dgt[t]], 1);
  else           atomicAdd(&cnt[32768 + dgs[t - 32768]], 1);
}
__global__ __launch_bounds__(256) void inv_kernel(const int* __restrict__ cnt,
                                                  float* __restrict__ igt,
                                                  float* __restrict__ igs) {
  int t = blockIdx.x * 256 + threadIdx.x;
  int c = cnt[t]; float v = 1.0f / (float)(c > 1 ? c : 1);
  if (t < 32768) igt[t] = v; else igs[t - 32768] = v;
}

// ---------------- encoder: out = relu(X @ W.T + b), fp32 in, bf16 + fp32 out ---------
// block = 64 rows x 128 cols, 4 waves (16 rows each), K chunked by 32.
template<int K>
__global__ __launch_bounds__(256) void enc_kernel(
    const float* __restrict__ X, const float* __restrict__ W,
    const float* __restrict__ bvec, bf16* __restrict__ out, float* __restrict__ out32)
{
  __shared__ bf16 Wl[4*128*8];   // 8KB; 16B-unit idx = q*128 + (n ^ q)
  const int tid = threadIdx.x;
  const int lane = tid & 63, wv = tid >> 6;
  const int r = lane & 15, g = lane >> 4;
  const long row = (long)blockIdx.x * 64 + wv * 16 + r;
  f32x4 acc[8] = {};
  for (int kc = 0; kc < K; kc += 32) {
    __syncthreads();
    for (int i = tid; i < 512; i += 256) {
      int q = i & 3, n = i >> 2;
      int k0 = kc + 8*q;
      f32x4 a = {}; f32x4 b2 = {};
      if (k0 < K)     a  = *(const f32x4*)(W + (long)n*K + k0);
      if (k0 + 4 < K) b2 = *(const f32x4*)(W + (long)n*K + k0 + 4);
      bf16x8 pk;
      #pragma unroll
      for (int j = 0; j < 4; j++) { pk[j] = (bf16)a[j]; pk[4+j] = (bf16)b2[j]; }
      *(bf16x8*)&Wl[(q*128 + (n ^ q)) * 8] = pk;
    }
    __syncthreads();
    int k0 = kc + 8*g;
    f32x4 a0 = {}, a1 = {};
    if (k0 < K)     a0 = *(const f32x4*)(X + row*K + k0);
    if (k0 + 4 < K) a1 = *(const f32x4*)(X + row*K + k0 + 4);
    bf16x8 af;
    #pragma unroll
    for (int j = 0; j < 4; j++) { af[j] = (bf16)a0[j]; af[4+j] = (bf16)a1[j]; }
    const bf16* bp = &Wl[(g*128 + (r ^ g)) * 8];
    #pragma unroll
    for (int c = 0; c < 8; c++) {
      bf16x8 bfr = *(const bf16x8*)(bp + c*128);
      acc[c] = mfma16(af, bfr, acc[c]);
    }
  }
  const long rb = (long)blockIdx.x * 64 + wv * 16 + 4 * g;
  #pragma unroll
  for (int c = 0; c < 8; c++) {
    int col = 16*c + r;
    float bb = bvec[col];
    #pragma unroll
    for (int j = 0; j < 4; j++) {
      float v = acc[c][j] + bb;
      v = v > 0.f ? v : 0.f;
      out[(rb + j)*128 + col] = (bf16)v;
      out32[(rb + j)*128 + col] = v;
    }
  }
}

// ---------------- generic 128x128 GEMM: C[M,128] = A[M,128] @ W.T (+epilogues) --------
// EPI: 0 = f32 out + bias (root GEMM -> "new")
//      1 = bf16 out, no bias (rel GEMM -> y)
//      2 = bf16 relu(acc + bias) (bt1; A fp32)
//      3 = acc + bias + res32 -> bf16 out AND f32 out2 (bt2 + residual -> x_base)
struct GDesc { const void* A; const bf16* W; const float* bias; const float* res32;
               void* out; void* out2; int nblk; };
struct GArgs { GDesc d[8]; };

template<int EPI, bool AF32, int NDESC>
__global__ __launch_bounds__(256) void gemm128_kernel(GArgs a)
{
  __shared__ bf16 Wl[16*128*8];  // 32KB; 16B-unit idx = q*128 + (n ^ (q&7))
  int b = blockIdx.x, di = 0;
  while (di + 1 < NDESC && b >= a.d[di].nblk) { b -= a.d[di].nblk; ++di; }
  const GDesc& D = a.d[di];
  const int tid = threadIdx.x;
  const int lane = tid & 63, wv = tid >> 6;
  const int r = lane & 15, g = lane >> 4;
  for (int i = tid; i < 2048; i += 256) {
    int q = i & 15, n = i >> 4;
    bf16x8 v = *(const bf16x8*)(D.W + n*128 + q*8);
    *(bf16x8*)&Wl[(q*128 + (n ^ (q & 7))) * 8] = v;
  }
  const long row = (long)b * 64 + wv * 16 + r;
  bf16x8 af[4];
  if constexpr (AF32) {
    const float* A = (const float*)D.A;
    #pragma unroll
    for (int kk = 0; kk < 4; kk++) {
      f32x4 a0 = *(const f32x4*)(A + row*128 + kk*32 + 8*g);
      f32x4 a1 = *(const f32x4*)(A + row*128 + kk*32 + 8*g + 4);
      #pragma unroll
      for (int j = 0; j < 4; j++) { af[kk][j] = (bf16)a0[j]; af[kk][4+j] = (bf16)a1[j]; }
    }
  } else {
    const bf16* A = (const bf16*)D.A;
    #pragma unroll
    for (int kk = 0; kk < 4; kk++)
      af[kk] = *(const bf16x8*)(A + row*128 + kk*32 + 8*g);
  }
  __syncthreads();
  f32x4 acc[8] = {};
  #pragma unroll
  for (int kk = 0; kk < 4; kk++) {
    int q = kk*4 + g;
    const bf16* bp = &Wl[(q*128 + (r ^ (q & 7))) * 8];
    #pragma unroll
    for (int c = 0; c < 8; c++) {
      bf16x8 bfr = *(const bf16x8*)(bp + c*128);
      acc[c] = mfma16(af[kk], bfr, acc[c]);
    }
  }
  const long rb = (long)b * 64 + wv * 16 + 4 * g;
  #pragma unroll
  for (int c = 0; c < 8; c++) {
    int col = 16*c + r;
    #pragma unroll
    for (int j = 0; j < 4; j++) {
      float v = acc[c][j];
      long oidx = (rb + j)*128 + col;
      if constexpr (EPI == 0) {
        ((float*)D.out)[oidx] = v + D.bias[col];
      } else if constexpr (EPI == 1) {
        ((bf16*)D.out)[oidx] = (bf16)v;
      } else if constexpr (EPI == 2) {
        v += D.bias[col];
        v = v > 0.f ? v : 0.f;
        ((bf16*)D.out)[oidx] = (bf16)v;
      } else {
        v += D.bias[col] + D.res32[oidx];
        ((bf16*)D.out)[oidx] = (bf16)v;
        ((float*)D.out2)[oidx] = v;
      }
    }
  }
}

// ---------------- edge scatter: new[dst] += y[src] * scale (all 8 types batched) ------
struct SDesc { const bf16* y; float* dst; const int* es; const int* ed; const float* inv; };
struct SArgs { SDesc d[8]; };

__global__ __launch_bounds__(256) void scatter_kernel(SArgs a)
{
  long t = (long)blockIdx.x * 256 + threadIdx.x;
  int slot = (int)(t >> 4);   // one edge per 16 lanes
  int l8 = (int)(t & 15);
  int di, e;
  if (slot < 131072)      { di = slot >> 15; e = slot & 32767; }
  else if (slot < 163840) { di = 4; e = slot - 131072; }
  else if (slot < 294912) { di = 5; e = slot - 163840; }
  else if (slot < 327680) { di = 6; e = slot - 294912; }
  else                    { di = 7; e = slot - 327680; }
  const SDesc& s = a.d[di];
  int src = s.es[e], dst = s.ed[e];
  float scale = 1.0f;
  if (s.inv) scale = s.inv[dst];
  bf16x8 v = *(const bf16x8*)(s.y + (long)src*128 + l8*8);
  float* op = s.dst + (long)dst*128 + l8*8;
  #pragma unroll
  for (int j = 0; j < 8; j++) unsafeAtomicAdd(op + j, (float)v[j] * scale);
}

// ------- joint/foot activation+residual: x32 = relu(new)+x32; x = bf16(x32) ----------
__global__ __launch_bounds__(256) void act_kernel(const float* __restrict__ nw,
                                                  float* __restrict__ x32,
                                                  bf16* __restrict__ x)
{
  long t = (long)blockIdx.x * 256 + threadIdx.x;
  long o = t * 8;
  f32x4 n0 = *(const f32x4*)(nw + o);
  f32x4 n1 = *(const f32x4*)(nw + o + 4);
  f32x4 x0 = *(const f32x4*)(x32 + o);
  f32x4 x1 = *(const f32x4*)(x32 + o + 4);
  bf16x8 ov;
  #pragma unroll
  for (int j = 0; j < 4; j++) {
    float v0 = (n0[j] > 0.f ? n0[j] : 0.f) + x0[j];
    float v1 = (n1[j] > 0.f ? n1[j] : 0.f) + x1[j];
    x0[j] = v0; x1[j] = v1;
    ov[j] = (bf16)v0; ov[4+j] = (bf16)v1;
  }
  *(f32x4*)(x32 + o) = x0;
  *(f32x4*)(x32 + o + 4) = x1;
  *(bf16x8*)(x + o) = ov;
}

// ---------------- decoder: out[8192,24] = xb32.view(8192,512) @ decW.T + b, * coeff ---
__global__ __launch_bounds__(256) void dec_kernel(const float* __restrict__ xb32,
    const float* __restrict__ W, const float* __restrict__ bvec,
    const float* __restrict__ clin, const float* __restrict__ cang,
    float* __restrict__ out)
{
  __shared__ float Wl[24*512];
  const int tid = threadIdx.x;
  for (int i = tid; i < 3072; i += 256)
    *(f32x4*)&Wl[i*4] = *(const f32x4*)(W + i*4);
  __syncthreads();
  const long row = (long)blockIdx.x * 256 + tid;
  float acc[24] = {};
  for (int k0 = 0; k0 < 512; k0 += 4) {
    f32x4 xv = *(const f32x4*)(xb32 + row*512 + k0);
    #pragma unroll
    for (int n = 0; n < 24; n++) {
      const float* wr = &Wl[n*512 + k0];
      float s = acc[n];
      #pragma unroll
      for (int j = 0; j < 4; j++) s += xv[j] * wr[j];
      acc[n] = s;
    }
  }
  #pragma unroll
  for (int n = 0; n < 24; n++) {
    int gq = n / 6, c = n - gq*6;
    float coef = (c < 3) ? clin[gq*3 + c] : cang[gq*3 + c - 3];
    out[row*24 + n] = (acc[n] + bvec[n]) * coef;
  }
}

// ===================================================================================
extern "C" void kernel_launch(void* const* d_in, const int* in_sizes, int n_in,
                              void* d_out, int out_size, void* d_ws, size_t ws_size,
                              hipStream_t stream)
{
  const float* x_base  = (const float*)d_in[0];
  const float* x_joint = (const float*)d_in[1];
  const float* x_foot  = (const float*)d_in[2];
  const float* eWb  = (const float*)d_in[3];
  const float* ebb  = (const float*)d_in[4];
  const float* eWj  = (const float*)d_in[5];
  const float* ebj  = (const float*)d_in[6];
  const float* eWf  = (const float*)d_in[7];
  const float* ebf  = (const float*)d_in[8];
  const float* Wrel  = (const float*)d_in[9];
  const float* Wroot = (const float*)d_in[10];
  const float* brel  = (const float*)d_in[11];
  const float* btW1  = (const float*)d_in[12];
  const float* btb1  = (const float*)d_in[13];
  const float* btW2  = (const float*)d_in[14];
  const float* btb2  = (const float*)d_in[15];
  const float* decW  = (const float*)d_in[16];
  const float* decb  = (const float*)d_in[17];
  const float* clin  = (const float*)d_in[18];
  const float* cang  = (const float*)d_in[19];
  const int* ei[8];
  for (int t = 0; t < 8; t++) ei[t] = (const int*)d_in[20 + t];
  const int Ecnt[8] = {32768, 32768, 32768, 32768, 32768, 131072, 32768, 32768};

  char* p = (char*)d_ws;
  auto alloc = [&](size_t bytes) { char* r = p; p += (bytes + 255) & ~(size_t)255; return r; };
  bf16*  xb    = (bf16*) alloc((size_t)NBASE  * 128 * 2);
  bf16*  xj    = (bf16*) alloc((size_t)NJOINT * 128 * 2);
  bf16*  xf    = (bf16*) alloc((size_t)NFOOT  * 128 * 2);
  float* xb32  = (float*)alloc((size_t)NBASE  * 128 * 4);
  float* xj32  = (float*)alloc((size_t)NJOINT * 128 * 4);   // xj32,xf32 contiguous
  float* xf32  = (float*)alloc((size_t)NFOOT  * 128 * 4);
  float* new_b = (float*)alloc((size_t)NBASE  * 128 * 4);
  float* new_j = (float*)alloc((size_t)NJOINT * 128 * 4);   // new_j,new_f contiguous
  float* new_f = (float*)alloc((size_t)NFOOT  * 128 * 4);
  const size_t ySrc[8] = {NBASE, NBASE, NBASE, NBASE, NJOINT, NJOINT, NJOINT, NFOOT};
  bf16* y[8];
  for (int t = 0; t < 8; t++) y[t] = (bf16*)alloc(ySrc[t] * 128 * 2);
  bf16*  hbt     = (bf16*) alloc((size_t)NBASE * 128 * 2);
  bf16*  Wrel_b  = (bf16*) alloc(4*8*16384*2);
  bf16*  Wroot_b = (bf16*) alloc(4*3*16384*2);
  bf16*  bt1_b   = (bf16*) alloc(16384*2);
  bf16*  bt2_b   = (bf16*) alloc(16384*2);
  float* bias_s  = (float*)alloc(4*3*128*4);
  float* inv_gt  = (float*)alloc((size_t)NBASE*4);
  float* inv_gs  = (float*)alloc((size_t)NBASE*4);
  int*   cnt     = (int*)  alloc((size_t)2*NBASE*4);
  (void)ws_size; (void)in_sizes; (void)n_in; (void)out_size;

  prep_kernel<<<2048, 256, 0, stream>>>(Wrel, Wroot, brel, btW1, btW2,
                                        Wrel_b, Wroot_b, bias_s, bt1_b, bt2_b);
  zero_kernel<<<256, 256, 0, stream>>>(cnt);
  hist_kernel<<<256, 256, 0, stream>>>(ei[0] + 32768, ei[1] + 32768, cnt);
  inv_kernel<<<256, 256, 0, stream>>>(cnt, inv_gt, inv_gs);

  enc_kernel<1800><<<512,  256, 0, stream>>>(x_base,  eWb, ebb, xb, xb32);
  enc_kernel<300> <<<1536, 256, 0, stream>>>(x_joint, eWj, ebj, xj, xj32);
  enc_kernel<900> <<<512,  256, 0, stream>>>(x_foot,  eWf, ebf, xf, xf32);

  const bf16* xsrc[8] = {xb, xb, xb, xb, xj, xj, xj, xf};
  float* ndst[8] = {new_b, new_b, new_b, new_j, new_b, new_j, new_f, new_j};
  const int nblkSrc[8] = {512, 512, 512, 512, 1536, 1536, 1536, 512};

  for (int l = 0; l < 4; l++) {
    GArgs ra = {};
    for (int t = 0; t < 8; t++)
      ra.d[t] = GDesc{ xsrc[t], Wrel_b + (l*8 + t)*16384, nullptr, nullptr, y[t], nullptr, nblkSrc[t] };
    gemm128_kernel<1, false, 8><<<7168, 256, 0, stream>>>(ra);

    GArgs ro = {};
    ro.d[0] = GDesc{ xb, Wroot_b + (l*3 + 0)*16384, bias_s + (l*3 + 0)*128, nullptr, new_b, nullptr, 512 };
    ro.d[1] = GDesc{ xj, Wroot_b + (l*3 + 1)*16384, bias_s + (l*3 + 1)*128, nullptr, new_j, nullptr, 1536 };
    ro.d[2] = GDesc{ xf, Wroot_b + (l*3 + 2)*16384, bias_s + (l*3 + 2)*128, nullptr, new_f, nullptr, 512 };
    gemm128_kernel<0, false, 3><<<2560, 256, 0, stream>>>(ro);

    SArgs sa = {};
    for (int t = 0; t < 8; t++)
      sa.d[t] = SDesc{ y[t], ndst[t], ei[t], ei[t] + Ecnt[t],
                       (t == 0 ? inv_gt : t == 1 ? inv_gs : nullptr) };
    scatter_kernel<<<22528, 256, 0, stream>>>(sa);

    GArgs b1 = {};
    b1.d[0] = GDesc{ new_b, bt1_b, btb1, nullptr, hbt, nullptr, 512 };
    gemm128_kernel<2, true, 1><<<512, 256, 0, stream>>>(b1);

    GArgs b2a = {};
    b2a.d[0] = GDesc{ hbt, bt2_b, btb2, xb32, xb, xb32, 512 };
    gemm128_kernel<3, false, 1><<<512, 256, 0, stream>>>(b2a);

    act_kernel<<<8192, 256, 0, stream>>>(new_j, xj32, xj);
  }

  dec_kernel<<<32, 256, 0, stream>>>(xb32, decW, decb, clin, cang, (float*)d_out);
}

// Round 3
// 1603.261 us; speedup vs baseline: 4.0142x; 4.0142x over previous
//
#include <hip/hip_runtime.h>

typedef __bf16 bf16;
typedef __attribute__((ext_vector_type(8))) __bf16 bf16x8;
typedef __attribute__((ext_vector_type(4))) float f32x4;
typedef __attribute__((ext_vector_type(4))) int   i32x4;

#define NBASE  32768
#define NJOINT 98304
#define NFOOT  32768
#define NSLOT  458752   // total (type,dst) slots: 3*NB + NJ + NB + NJ + NB + NJ
#define NEDGE  360448   // total edges across 8 types
#define SCAN_BLOCKS 448 // NSLOT / 1024 exactly

static __device__ __forceinline__ f32x4 mfma16(bf16x8 a, bf16x8 b, f32x4 c) {
  return __builtin_amdgcn_mfma_f32_16x16x32_bf16(a, b, c, 0, 0, 0);
}

// slot decomposition over the 8 edge types (t5 has 131072 edges, rest 32768)
static __device__ __forceinline__ void edge_decomp(int slot, int& ty, int& e) {
  if (slot < 131072)      { ty = slot >> 15; e = slot & 32767; }
  else if (slot < 163840) { ty = 4; e = slot - 131072; }
  else if (slot < 294912) { ty = 5; e = slot - 163840; }
  else if (slot < 327680) { ty = 6; e = slot - 294912; }
  else                    { ty = 7; e = slot - 327680; }
}
static __device__ __forceinline__ int type_off(int ty) {
  return ty==0?0: ty==1?32768: ty==2?65536: ty==3?98304:
         ty==4?196608: ty==5?229376: ty==6?327680: 360448;
}

struct EArgs { const int* e0; const int* e1; const int* e2; const int* e3;
               const int* e4; const int* e5; const int* e6; const int* e7; };
static __device__ __forceinline__ const int* esel(const EArgs& a, int ty) {
  const int* p = a.e0;
  if (ty==1) p=a.e1; if (ty==2) p=a.e2; if (ty==3) p=a.e3;
  if (ty==4) p=a.e4; if (ty==5) p=a.e5; if (ty==6) p=a.e6; if (ty==7) p=a.e7;
  return p;
}

// ---------------- weight prep: fp32->bf16, Wroot/bias pre-summed per dst ----------------
__global__ __launch_bounds__(256) void prep_kernel(
    const float* __restrict__ Wrel, const float* __restrict__ Wroot,
    const float* __restrict__ brel, const float* __restrict__ bt1,
    const float* __restrict__ bt2,
    bf16* __restrict__ Wrel_b, bf16* __restrict__ Wroot_b,
    float* __restrict__ bias_s, bf16* __restrict__ bt1_b, bf16* __restrict__ bt2_b)
{
  int t = blockIdx.x * 256 + threadIdx.x;
  if (t < 4*8*16384) Wrel_b[t] = (bf16)Wrel[t];
  if (t < 4*3*16384) {
    int i = t & 16383; int ld = t >> 14; int l = ld / 3, dt = ld - l*3;
    const float* Wb = Wroot + l * 8 * 16384;
    float s;
    if (dt == 0)      s = Wb[0*16384+i] + Wb[1*16384+i] + Wb[2*16384+i] + Wb[4*16384+i];
    else if (dt == 1) s = Wb[3*16384+i] + Wb[5*16384+i] + Wb[7*16384+i];
    else              s = Wb[6*16384+i];
    Wroot_b[t] = (bf16)s;
  }
  if (t < 16384) { bt1_b[t] = (bf16)bt1[t]; bt2_b[t] = (bf16)bt2[t]; }
  if (t < 4*3*128) {
    int c = t & 127; int ld = t >> 7; int l = ld / 3, dt = ld - l*3;
    const float* B = brel + l * 8 * 128;
    float s;
    if (dt == 0)      s = B[0*128+c] + B[1*128+c] + B[2*128+c] + B[4*128+c];
    else if (dt == 1) s = B[3*128+c] + B[5*128+c] + B[7*128+c];
    else              s = B[6*128+c];
    bias_s[t] = s;
  }
}

// ---------------- CSR build: zero -> hist -> scan(A/B/C) -> fill ----------------
__global__ __launch_bounds__(256) void zero_kernel(int* cnt) {
  cnt[blockIdx.x * 256 + threadIdx.x] = 0;
}

__global__ __launch_bounds__(256) void hist8_kernel(EArgs a, int* __restrict__ cnt) {
  int slot = blockIdx.x * 256 + threadIdx.x;   // grid covers exactly NEDGE
  int ty, e; edge_decomp(slot, ty, e);
  const int* ep = esel(a, ty);
  int ecnt = (ty == 5) ? 131072 : 32768;
  int dst = ep[ecnt + e];
  atomicAdd(&cnt[type_off(ty) + dst], 1);
}

__global__ __launch_bounds__(256) void scanA_kernel(const int* __restrict__ cnt, int* __restrict__ bsum) {
  __shared__ int red[256];
  int base = blockIdx.x * 1024 + threadIdx.x * 4;
  i32x4 v = *(const i32x4*)(cnt + base);
  red[threadIdx.x] = v[0] + v[1] + v[2] + v[3];
  __syncthreads();
  for (int d = 128; d > 0; d >>= 1) {
    if (threadIdx.x < d) red[threadIdx.x] += red[threadIdx.x + d];
    __syncthreads();
  }
  if (threadIdx.x == 0) bsum[blockIdx.x] = red[0];
}

__global__ __launch_bounds__(256) void scanB_kernel(const int* __restrict__ bsum, int* __restrict__ bscan) {
  __shared__ int s[SCAN_BLOCKS];
  int i0 = threadIdx.x, i1 = threadIdx.x + 256;
  bool h1 = (i1 < SCAN_BLOCKS);
  s[i0] = bsum[i0];
  if (h1) s[i1] = bsum[i1];
  __syncthreads();
  for (int d = 1; d < SCAN_BLOCKS; d <<= 1) {
    int v0 = 0, v1 = 0;
    if (i0 >= d) v0 = s[i0 - d];
    if (h1 && i1 >= d) v1 = s[i1 - d];
    __syncthreads();
    s[i0] += v0;
    if (h1) s[i1] += v1;
    __syncthreads();
  }
  bscan[i0] = i0 ? s[i0 - 1] : 0;
  if (h1) bscan[i1] = s[i1 - 1];
}

__global__ __launch_bounds__(256) void scanC_kernel(const int* __restrict__ cnt,
    const int* __restrict__ bscan, int* __restrict__ rowptr, int* __restrict__ cursor)
{
  __shared__ int toff[256];
  int base = blockIdx.x * 1024 + threadIdx.x * 4;
  i32x4 v = *(const i32x4*)(cnt + base);
  int tsum = v[0] + v[1] + v[2] + v[3];
  toff[threadIdx.x] = tsum;
  __syncthreads();
  for (int d = 1; d < 256; d <<= 1) {
    int t = 0;
    if (threadIdx.x >= d) t = toff[threadIdx.x - d];
    __syncthreads();
    toff[threadIdx.x] += t;
    __syncthreads();
  }
  int off = bscan[blockIdx.x] + toff[threadIdx.x] - tsum;   // exclusive
  i32x4 r;
  r[0] = off; r[1] = off + v[0]; r[2] = off + v[0] + v[1]; r[3] = off + v[0] + v[1] + v[2];
  *(i32x4*)(rowptr + base) = r;
  *(i32x4*)(cursor + base) = r;
  if (blockIdx.x == SCAN_BLOCKS - 1 && threadIdx.x == 255) rowptr[NSLOT] = NEDGE;
}

__global__ __launch_bounds__(256) void fill_kernel(EArgs a, int* __restrict__ cursor,
                                                   int* __restrict__ perm) {
  int slot = blockIdx.x * 256 + threadIdx.x;
  int ty, e; edge_decomp(slot, ty, e);
  const int* ep = esel(a, ty);
  int ecnt = (ty == 5) ? 131072 : 32768;
  int src = ep[e];
  int dst = ep[ecnt + e];
  int pos = atomicAdd(&cursor[type_off(ty) + dst], 1);
  perm[pos] = src;
}

// ---------------- encoder: out = relu(X @ W.T + b), fp32 in, bf16 + fp32 out ---------
template<int K>
__global__ __launch_bounds__(256) void enc_kernel(
    const float* __restrict__ X, const float* __restrict__ W,
    const float* __restrict__ bvec, bf16* __restrict__ out, float* __restrict__ out32)
{
  __shared__ bf16 Wl[4*128*8];   // 8KB; 16B-unit idx = q*128 + (n ^ q)
  const int tid = threadIdx.x;
  const int lane = tid & 63, wv = tid >> 6;
  const int r = lane & 15, g = lane >> 4;
  const long row = (long)blockIdx.x * 64 + wv * 16 + r;
  f32x4 acc[8] = {};
  for (int kc = 0; kc < K; kc += 32) {
    __syncthreads();
    for (int i = tid; i < 512; i += 256) {
      int q = i & 3, n = i >> 2;
      int k0 = kc + 8*q;
      f32x4 a = {}; f32x4 b2 = {};
      if (k0 < K)     a  = *(const f32x4*)(W + (long)n*K + k0);
      if (k0 + 4 < K) b2 = *(const f32x4*)(W + (long)n*K + k0 + 4);
      bf16x8 pk;
      #pragma unroll
      for (int j = 0; j < 4; j++) { pk[j] = (bf16)a[j]; pk[4+j] = (bf16)b2[j]; }
      *(bf16x8*)&Wl[(q*128 + (n ^ q)) * 8] = pk;
    }
    __syncthreads();
    int k0 = kc + 8*g;
    f32x4 a0 = {}, a1 = {};
    if (k0 < K)     a0 = *(const f32x4*)(X + row*K + k0);
    if (k0 + 4 < K) a1 = *(const f32x4*)(X + row*K + k0 + 4);
    bf16x8 af;
    #pragma unroll
    for (int j = 0; j < 4; j++) { af[j] = (bf16)a0[j]; af[4+j] = (bf16)a1[j]; }
    const bf16* bp = &Wl[(g*128 + (r ^ g)) * 8];
    #pragma unroll
    for (int c = 0; c < 8; c++) {
      bf16x8 bfr = *(const bf16x8*)(bp + c*128);
      acc[c] = mfma16(af, bfr, acc[c]);
    }
  }
  const long rb = (long)blockIdx.x * 64 + wv * 16 + 4 * g;
  #pragma unroll
  for (int c = 0; c < 8; c++) {
    int col = 16*c + r;
    float bb = bvec[col];
    #pragma unroll
    for (int j = 0; j < 4; j++) {
      float v = acc[c][j] + bb;
      v = v > 0.f ? v : 0.f;
      out[(rb + j)*128 + col] = (bf16)v;
      out32[(rb + j)*128 + col] = v;
    }
  }
}

// ---------------- generic 128x128 GEMM: C[M,128] = A[M,128] @ W.T (+epilogues) --------
// EPI: 0 = f32 out + bias (root GEMM -> root contribution)
//      1 = bf16 out, no bias (rel GEMM -> y)
//      2 = bf16 relu(acc + bias) (bt1; A fp32)
//      3 = acc + bias + res32 -> bf16 out AND f32 out2 (bt2 + residual -> x_base)
struct GDesc { const void* A; const bf16* W; const float* bias; const float* res32;
               void* out; void* out2; int nblk; };
struct GArgs { GDesc d[8]; };

template<int EPI, bool AF32, int NDESC>
__global__ __launch_bounds__(256) void gemm128_kernel(GArgs a)
{
  __shared__ bf16 Wl[16*128*8];  // 32KB; 16B-unit idx = q*128 + (n ^ (q&7))
  int b = blockIdx.x, di = 0;
  while (di + 1 < NDESC && b >= a.d[di].nblk) { b -= a.d[di].nblk; ++di; }
  const GDesc& D = a.d[di];
  const int tid = threadIdx.x;
  const int lane = tid & 63, wv = tid >> 6;
  const int r = lane & 15, g = lane >> 4;
  for (int i = tid; i < 2048; i += 256) {
    int q = i & 15, n = i >> 4;
    bf16x8 v = *(const bf16x8*)(D.W + n*128 + q*8);
    *(bf16x8*)&Wl[(q*128 + (n ^ (q & 7))) * 8] = v;
  }
  const long row = (long)b * 64 + wv * 16 + r;
  bf16x8 af[4];
  if constexpr (AF32) {
    const float* A = (const float*)D.A;
    #pragma unroll
    for (int kk = 0; kk < 4; kk++) {
      f32x4 a0 = *(const f32x4*)(A + row*128 + kk*32 + 8*g);
      f32x4 a1 = *(const f32x4*)(A + row*128 + kk*32 + 8*g + 4);
      #pragma unroll
      for (int j = 0; j < 4; j++) { af[kk][j] = (bf16)a0[j]; af[kk][4+j] = (bf16)a1[j]; }
    }
  } else {
    const bf16* A = (const bf16*)D.A;
    #pragma unroll
    for (int kk = 0; kk < 4; kk++)
      af[kk] = *(const bf16x8*)(A + row*128 + kk*32 + 8*g);
  }
  __syncthreads();
  f32x4 acc[8] = {};
  #pragma unroll
  for (int kk = 0; kk < 4; kk++) {
    int q = kk*4 + g;
    const bf16* bp = &Wl[(q*128 + (r ^ (q & 7))) * 8];
    #pragma unroll
    for (int c = 0; c < 8; c++) {
      bf16x8 bfr = *(const bf16x8*)(bp + c*128);
      acc[c] = mfma16(af[kk], bfr, acc[c]);
    }
  }
  const long rb = (long)b * 64 + wv * 16 + 4 * g;
  #pragma unroll
  for (int c = 0; c < 8; c++) {
    int col = 16*c + r;
    #pragma unroll
    for (int j = 0; j < 4; j++) {
      float v = acc[c][j];
      long oidx = (rb + j)*128 + col;
      if constexpr (EPI == 0) {
        ((float*)D.out)[oidx] = v + D.bias[col];
      } else if constexpr (EPI == 1) {
        ((bf16*)D.out)[oidx] = (bf16)v;
      } else if constexpr (EPI == 2) {
        v += D.bias[col];
        v = v > 0.f ? v : 0.f;
        ((bf16*)D.out)[oidx] = (bf16)v;
      } else {
        v += D.bias[col] + D.res32[oidx];
        ((bf16*)D.out)[oidx] = (bf16)v;
        ((float*)D.out2)[oidx] = v;
      }
    }
  }
}

// ---------------- CSR-gather aggregation (atomic-free) --------------------------------
// KIND 0 (base):  new_b[n] = root[n] + mean(y0) + mean(y1) + sum(y2) + sum(y4)  [fp32 out]
// KIND 1 (joint): x32 += relu(root[n] + sum(y3)+sum(y5)+sum(y7)); x16 = bf16(x32)
// KIND 2 (foot):  x32 += relu(root[n] + sum(y6)); x16 = bf16(x32)
struct AArgs { const bf16* y[4]; const float* root; float* o32; bf16* o16; };

template<int KIND>
__global__ __launch_bounds__(256) void agg_kernel(AArgs a,
    const int* __restrict__ rowptr, const int* __restrict__ perm)
{
  constexpr int NT = (KIND==0) ? 4 : ((KIND==1) ? 3 : 1);
  constexpr int OFFS[3][4] = {{0, 32768, 65536, 196608},
                              {98304, 229376, 360448, 0},
                              {327680, 0, 0, 0}};
  const int tid = threadIdx.x;
  const int lane = tid & 63, wv = tid >> 6;
  const int l8 = lane & 15, g = lane >> 4;
  const int node = blockIdx.x * 16 + wv * 4 + g;
  const long co = (long)node * 128 + l8 * 8;
  f32x4 a0 = *(const f32x4*)(a.root + co);
  f32x4 a1 = *(const f32x4*)(a.root + co + 4);
  #pragma unroll
  for (int ti = 0; ti < NT; ++ti) {
    const int slot = OFFS[KIND][ti] + node;
    int rp0 = rowptr[slot], rp1 = rowptr[slot + 1];
    float sc = 1.0f;
    if (KIND == 0 && ti < 2) {          // mean aggregation (gt, gs)
      int d = rp1 - rp0;
      sc = d > 0 ? 1.0f / (float)d : 1.0f;
    }
    const bf16* yb = a.y[ti];
    for (int e = rp0; e < rp1; ++e) {
      int src = perm[e];
      bf16x8 v = *(const bf16x8*)(yb + (long)src * 128 + l8 * 8);
      #pragma unroll
      for (int j = 0; j < 4; j++) {
        a0[j] += (float)v[j]   * sc;
        a1[j] += (float)v[4+j] * sc;
      }
    }
  }
  if constexpr (KIND == 0) {
    *(f32x4*)(a.o32 + co)     = a0;
    *(f32x4*)(a.o32 + co + 4) = a1;
  } else {
    f32x4 x0 = *(const f32x4*)(a.o32 + co);
    f32x4 x1 = *(const f32x4*)(a.o32 + co + 4);
    bf16x8 ov;
    #pragma unroll
    for (int j = 0; j < 4; j++) {
      float v0 = (a0[j] > 0.f ? a0[j] : 0.f) + x0[j];
      float v1 = (a1[j] > 0.f ? a1[j] : 0.f) + x1[j];
      x0[j] = v0; x1[j] = v1;
      ov[j] = (bf16)v0; ov[4+j] = (bf16)v1;
    }
    *(f32x4*)(a.o32 + co)     = x0;
    *(f32x4*)(a.o32 + co + 4) = x1;
    *(bf16x8*)(a.o16 + co)    = ov;
  }
}

// ---------------- decoder: out[8192,24] = xb32.view(8192,512) @ decW.T + b, * coeff ---
__global__ __launch_bounds__(256) void dec_kernel(const float* __restrict__ xb32,
    const float* __restrict__ W, const float* __restrict__ bvec,
    const float* __restrict__ clin, const float* __restrict__ cang,
    float* __restrict__ out)
{
  __shared__ float Wl[24*512];
  const int tid = threadIdx.x;
  for (int i = tid; i < 3072; i += 256)
    *(f32x4*)&Wl[i*4] = *(const f32x4*)(W + i*4);
  __syncthreads();
  const long row = (long)blockIdx.x * 256 + tid;
  float acc[24] = {};
  for (int k0 = 0; k0 < 512; k0 += 4) {
    f32x4 xv = *(const f32x4*)(xb32 + row*512 + k0);
    #pragma unroll
    for (int n = 0; n < 24; n++) {
      const float* wr = &Wl[n*512 + k0];
      float s = acc[n];
      #pragma unroll
      for (int j = 0; j < 4; j++) s += xv[j] * wr[j];
      acc[n] = s;
    }
  }
  #pragma unroll
  for (int n = 0; n < 24; n++) {
    int gq = n / 6, c = n - gq*6;
    float coef = (c < 3) ? clin[gq*3 + c] : cang[gq*3 + c - 3];
    out[row*24 + n] = (acc[n] + bvec[n]) * coef;
  }
}

// ===================================================================================
extern "C" void kernel_launch(void* const* d_in, const int* in_sizes, int n_in,
                              void* d_out, int out_size, void* d_ws, size_t ws_size,
                              hipStream_t stream)
{
  const float* x_base  = (const float*)d_in[0];
  const float* x_joint = (const float*)d_in[1];
  const float* x_foot  = (const float*)d_in[2];
  const float* eWb  = (const float*)d_in[3];
  const float* ebb  = (const float*)d_in[4];
  const float* eWj  = (const float*)d_in[5];
  const float* ebj  = (const float*)d_in[6];
  const float* eWf  = (const float*)d_in[7];
  const float* ebf  = (const float*)d_in[8];
  const float* Wrel  = (const float*)d_in[9];
  const float* Wroot = (const float*)d_in[10];
  const float* brel  = (const float*)d_in[11];
  const float* btW1  = (const float*)d_in[12];
  const float* btb1  = (const float*)d_in[13];
  const float* btW2  = (const float*)d_in[14];
  const float* btb2  = (const float*)d_in[15];
  const float* decW  = (const float*)d_in[16];
  const float* decb  = (const float*)d_in[17];
  const float* clin  = (const float*)d_in[18];
  const float* cang  = (const float*)d_in[19];
  const int* ei[8];
  for (int t = 0; t < 8; t++) ei[t] = (const int*)d_in[20 + t];

  char* p = (char*)d_ws;
  auto alloc = [&](size_t bytes) { char* r = p; p += (bytes + 255) & ~(size_t)255; return r; };
  bf16*  xb    = (bf16*) alloc((size_t)NBASE  * 128 * 2);
  bf16*  xj    = (bf16*) alloc((size_t)NJOINT * 128 * 2);
  bf16*  xf    = (bf16*) alloc((size_t)NFOOT  * 128 * 2);
  float* xb32  = (float*)alloc((size_t)NBASE  * 128 * 4);
  float* xj32  = (float*)alloc((size_t)NJOINT * 128 * 4);
  float* xf32  = (float*)alloc((size_t)NFOOT  * 128 * 4);
  float* new_b = (float*)alloc((size_t)NBASE  * 128 * 4);
  float* new_j = (float*)alloc((size_t)NJOINT * 128 * 4);
  float* new_f = (float*)alloc((size_t)NFOOT  * 128 * 4);
  const size_t ySrc[8] = {NBASE, NBASE, NBASE, NBASE, NJOINT, NJOINT, NJOINT, NFOOT};
  bf16* y[8];
  for (int t = 0; t < 8; t++) y[t] = (bf16*)alloc(ySrc[t] * 128 * 2);
  bf16*  hbt     = (bf16*) alloc((size_t)NBASE * 128 * 2);
  bf16*  Wrel_b  = (bf16*) alloc(4*8*16384*2);
  bf16*  Wroot_b = (bf16*) alloc(4*3*16384*2);
  bf16*  bt1_b   = (bf16*) alloc(16384*2);
  bf16*  bt2_b   = (bf16*) alloc(16384*2);
  float* bias_s  = (float*)alloc(4*3*128*4);
  int*   cnt     = (int*)  alloc((size_t)NSLOT*4);
  int*   rowptr  = (int*)  alloc((size_t)(NSLOT+1)*4);
  int*   cursor  = (int*)  alloc((size_t)NSLOT*4);
  int*   perm    = (int*)  alloc((size_t)NEDGE*4);
  int*   bsum    = (int*)  alloc((size_t)SCAN_BLOCKS*4);
  int*   bscan   = (int*)  alloc((size_t)SCAN_BLOCKS*4);
  (void)ws_size; (void)in_sizes; (void)n_in; (void)out_size;

  EArgs ea = { ei[0], ei[1], ei[2], ei[3], ei[4], ei[5], ei[6], ei[7] };

  prep_kernel<<<2048, 256, 0, stream>>>(Wrel, Wroot, brel, btW1, btW2,
                                        Wrel_b, Wroot_b, bias_s, bt1_b, bt2_b);
  zero_kernel<<<NSLOT/256, 256, 0, stream>>>(cnt);
  hist8_kernel<<<NEDGE/256, 256, 0, stream>>>(ea, cnt);
  scanA_kernel<<<SCAN_BLOCKS, 256, 0, stream>>>(cnt, bsum);
  scanB_kernel<<<1, 256, 0, stream>>>(bsum, bscan);
  scanC_kernel<<<SCAN_BLOCKS, 256, 0, stream>>>(cnt, bscan, rowptr, cursor);
  fill_kernel<<<NEDGE/256, 256, 0, stream>>>(ea, cursor, perm);

  enc_kernel<1800><<<512,  256, 0, stream>>>(x_base,  eWb, ebb, xb, xb32);
  enc_kernel<300> <<<1536, 256, 0, stream>>>(x_joint, eWj, ebj, xj, xj32);
  enc_kernel<900> <<<512,  256, 0, stream>>>(x_foot,  eWf, ebf, xf, xf32);

  const bf16* xsrc[8] = {xb, xb, xb, xb, xj, xj, xj, xf};
  const int nblkSrc[8] = {512, 512, 512, 512, 1536, 1536, 1536, 512};

  for (int l = 0; l < 4; l++) {
    GArgs ra = {};
    for (int t = 0; t < 8; t++)
      ra.d[t] = GDesc{ xsrc[t], Wrel_b + (l*8 + t)*16384, nullptr, nullptr, y[t], nullptr, nblkSrc[t] };
    gemm128_kernel<1, false, 8><<<7168, 256, 0, stream>>>(ra);

    GArgs ro = {};
    ro.d[0] = GDesc{ xb, Wroot_b + (l*3 + 0)*16384, bias_s + (l*3 + 0)*128, nullptr, new_b, nullptr, 512 };
    ro.d[1] = GDesc{ xj, Wroot_b + (l*3 + 1)*16384, bias_s + (l*3 + 1)*128, nullptr, new_j, nullptr, 1536 };
    ro.d[2] = GDesc{ xf, Wroot_b + (l*3 + 2)*16384, bias_s + (l*3 + 2)*128, nullptr, new_f, nullptr, 512 };
    gemm128_kernel<0, false, 3><<<2560, 256, 0, stream>>>(ro);

    AArgs ab = { { y[0], y[1], y[2], y[4] }, new_b, new_b, nullptr };
    agg_kernel<0><<<NBASE/16, 256, 0, stream>>>(ab, rowptr, perm);
    AArgs aj = { { y[3], y[5], y[7], nullptr }, new_j, xj32, xj };
    agg_kernel<1><<<NJOINT/16, 256, 0, stream>>>(aj, rowptr, perm);
    AArgs af = { { y[6], nullptr, nullptr, nullptr }, new_f, xf32, xf };
    agg_kernel<2><<<NFOOT/16, 256, 0, stream>>>(af, rowptr, perm);

    GArgs b1 = {};
    b1.d[0] = GDesc{ new_b, bt1_b, btb1, nullptr, hbt, nullptr, 512 };
    gemm128_kernel<2, true, 1><<<512, 256, 0, stream>>>(b1);

    GArgs b2a = {};
    b2a.d[0] = GDesc{ hbt, bt2_b, btb2, xb32, xb, xb32, 512 };
    gemm128_kernel<3, false, 1><<<512, 256, 0, stream>>>(b2a);
  }

  dec_kernel<<<32, 256, 0, stream>>>(xb32, decW, decb, clin, cang, (float*)d_out);
}

// Round 5
// 1478.789 us; speedup vs baseline: 4.3520x; 1.0842x over previous
//
#include <hip/hip_runtime.h>

typedef __bf16 bf16;
typedef __attribute__((ext_vector_type(8))) __bf16 bf16x8;
typedef __attribute__((ext_vector_type(4))) float f32x4;
typedef __attribute__((ext_vector_type(4))) int   i32x4;

#define NBASE  32768
#define NJOINT 98304
#define NFOOT  32768
#define NSLOT  458752   // total (type,dst) slots: 3*NB + NJ + NB + NJ + NB + NJ
#define NEDGE  360448   // total edges across 8 types
#define SCAN_BLOCKS 448 // NSLOT / 1024 exactly

static __device__ __forceinline__ f32x4 mfma16(bf16x8 a, bf16x8 b, f32x4 c) {
  return __builtin_amdgcn_mfma_f32_16x16x32_bf16(a, b, c, 0, 0, 0);
}

// slot decomposition over the 8 edge types (t5 has 131072 edges, rest 32768)
static __device__ __forceinline__ void edge_decomp(int slot, int& ty, int& e) {
  if (slot < 131072)      { ty = slot >> 15; e = slot & 32767; }
  else if (slot < 163840) { ty = 4; e = slot - 131072; }
  else if (slot < 294912) { ty = 5; e = slot - 163840; }
  else if (slot < 327680) { ty = 6; e = slot - 294912; }
  else                    { ty = 7; e = slot - 327680; }
}
static __device__ __forceinline__ int type_off(int ty) {
  return ty==0?0: ty==1?32768: ty==2?65536: ty==3?98304:
         ty==4?196608: ty==5?229376: ty==6?327680: 360448;
}

struct EArgs { const int* e0; const int* e1; const int* e2; const int* e3;
               const int* e4; const int* e5; const int* e6; const int* e7; };
static __device__ __forceinline__ const int* esel(const EArgs& a, int ty) {
  const int* p = a.e0;
  if (ty==1) p=a.e1; if (ty==2) p=a.e2; if (ty==3) p=a.e3;
  if (ty==4) p=a.e4; if (ty==5) p=a.e5; if (ty==6) p=a.e6; if (ty==7) p=a.e7;
  return p;
}

// ---------------- weight prep: fp32->bf16, Wroot/bias pre-summed, enc W padded -------
__global__ __launch_bounds__(256) void prep_kernel(
    const float* __restrict__ Wrel, const float* __restrict__ Wroot,
    const float* __restrict__ brel, const float* __restrict__ bt1,
    const float* __restrict__ bt2,
    const float* __restrict__ eWb, const float* __restrict__ eWj,
    const float* __restrict__ eWf,
    bf16* __restrict__ Wrel_b, bf16* __restrict__ Wroot_b,
    float* __restrict__ bias_s, bf16* __restrict__ bt1_b, bf16* __restrict__ bt2_b,
    bf16* __restrict__ eWb_p, bf16* __restrict__ eWj_p, bf16* __restrict__ eWf_p)
{
  int t = blockIdx.x * 256 + threadIdx.x;
  if (t < 4*8*16384) Wrel_b[t] = (bf16)Wrel[t];
  if (t < 4*3*16384) {
    int i = t & 16383; int ld = t >> 14; int l = ld / 3, dt = ld - l*3;
    const float* Wb = Wroot + l * 8 * 16384;
    float s;
    if (dt == 0)      s = Wb[0*16384+i] + Wb[1*16384+i] + Wb[2*16384+i] + Wb[4*16384+i];
    else if (dt == 1) s = Wb[3*16384+i] + Wb[5*16384+i] + Wb[7*16384+i];
    else              s = Wb[6*16384+i];
    Wroot_b[t] = (bf16)s;
  }
  if (t < 16384) { bt1_b[t] = (bf16)bt1[t]; bt2_b[t] = (bf16)bt2[t]; }
  if (t < 4*3*128) {
    int c = t & 127; int ld = t >> 7; int l = ld / 3, dt = ld - l*3;
    const float* B = brel + l * 8 * 128;
    float s;
    if (dt == 0)      s = B[0*128+c] + B[1*128+c] + B[2*128+c] + B[4*128+c];
    else if (dt == 1) s = B[3*128+c] + B[5*128+c] + B[7*128+c];
    else              s = B[6*128+c];
    bias_s[t] = s;
  }
  // encoder weights, padded with zeros to KP
  if (t < 128*1920) { int n = t / 1920, k = t - n*1920;
    eWb_p[t] = (bf16)(k < 1800 ? eWb[n*1800 + k] : 0.f); }
  if (t < 128*384)  { int n = t / 384, k = t - n*384;
    eWj_p[t] = (bf16)(k < 300 ? eWj[n*300 + k] : 0.f); }
  if (t < 128*1024) { int n = t >> 10, k = t & 1023;
    eWf_p[t] = (bf16)(k < 900 ? eWf[n*900 + k] : 0.f); }
}

// ---------------- CSR build: zero -> hist -> scan(A/B/C) -> fill ----------------
__global__ __launch_bounds__(256) void zero_kernel(int* cnt) {
  cnt[blockIdx.x * 256 + threadIdx.x] = 0;
}

__global__ __launch_bounds__(256) void hist8_kernel(EArgs a, int* __restrict__ cnt) {
  int slot = blockIdx.x * 256 + threadIdx.x;   // grid covers exactly NEDGE
  int ty, e; edge_decomp(slot, ty, e);
  const int* ep = esel(a, ty);
  int ecnt = (ty == 5) ? 131072 : 32768;
  int dst = ep[ecnt + e];
  atomicAdd(&cnt[type_off(ty) + dst], 1);
}

__global__ __launch_bounds__(256) void scanA_kernel(const int* __restrict__ cnt, int* __restrict__ bsum) {
  __shared__ int red[256];
  int base = blockIdx.x * 1024 + threadIdx.x * 4;
  i32x4 v = *(const i32x4*)(cnt + base);
  red[threadIdx.x] = v[0] + v[1] + v[2] + v[3];
  __syncthreads();
  for (int d = 128; d > 0; d >>= 1) {
    if (threadIdx.x < d) red[threadIdx.x] += red[threadIdx.x + d];
    __syncthreads();
  }
  if (threadIdx.x == 0) bsum[blockIdx.x] = red[0];
}

__global__ __launch_bounds__(256) void scanB_kernel(const int* __restrict__ bsum, int* __restrict__ bscan) {
  __shared__ int s[SCAN_BLOCKS];
  int i0 = threadIdx.x, i1 = threadIdx.x + 256;
  bool h1 = (i1 < SCAN_BLOCKS);
  s[i0] = bsum[i0];
  if (h1) s[i1] = bsum[i1];
  __syncthreads();
  for (int d = 1; d < SCAN_BLOCKS; d <<= 1) {
    int v0 = 0, v1 = 0;
    if (i0 >= d) v0 = s[i0 - d];
    if (h1 && i1 >= d) v1 = s[i1 - d];
    __syncthreads();
    s[i0] += v0;
    if (h1) s[i1] += v1;
    __syncthreads();
  }
  bscan[i0] = i0 ? s[i0 - 1] : 0;
  if (h1) bscan[i1] = s[i1 - 1];
}

__global__ __launch_bounds__(256) void scanC_kernel(const int* __restrict__ cnt,
    const int* __restrict__ bscan, int* __restrict__ rowptr, int* __restrict__ cursor)
{
  __shared__ int toff[256];
  int base = blockIdx.x * 1024 + threadIdx.x * 4;
  i32x4 v = *(const i32x4*)(cnt + base);
  int tsum = v[0] + v[1] + v[2] + v[3];
  toff[threadIdx.x] = tsum;
  __syncthreads();
  for (int d = 1; d < 256; d <<= 1) {
    int t = 0;
    if (threadIdx.x >= d) t = toff[threadIdx.x - d];
    __syncthreads();
    toff[threadIdx.x] += t;
    __syncthreads();
  }
  int off = bscan[blockIdx.x] + toff[threadIdx.x] - tsum;   // exclusive
  i32x4 r;
  r[0] = off; r[1] = off + v[0]; r[2] = off + v[0] + v[1]; r[3] = off + v[0] + v[1] + v[2];
  *(i32x4*)(rowptr + base) = r;
  *(i32x4*)(cursor + base) = r;
  if (blockIdx.x == SCAN_BLOCKS - 1 && threadIdx.x == 255) rowptr[NSLOT] = NEDGE;
}

__global__ __launch_bounds__(256) void fill_kernel(EArgs a, int* __restrict__ cursor,
                                                   int* __restrict__ perm) {
  int slot = blockIdx.x * 256 + threadIdx.x;
  int ty, e; edge_decomp(slot, ty, e);
  const int* ep = esel(a, ty);
  int ecnt = (ty == 5) ? 131072 : 32768;
  int src = ep[e];
  int dst = ep[ecnt + e];
  int pos = atomicAdd(&cursor[type_off(ty) + dst], 1);
  perm[pos] = src;
}

// ------- encoder v2: 2-phase pipelined streaming GEMM, one barrier per 128-K slice ----
// out = relu(X @ Wp.T + b); Wp bf16 padded to KP (zeros); block = 64 rows, 4 waves.
template<int K, int KP>
__global__ __launch_bounds__(256) void enc2_kernel(
    const float* __restrict__ X, const bf16* __restrict__ Wp,
    const float* __restrict__ bvec, bf16* __restrict__ out, float* __restrict__ out32)
{
  constexpr int S = KP / 128;                 // number of K slices
  __shared__ bf16 Wl[2][2048 * 8];            // 2 x 32KB double buffer
  const int tid = threadIdx.x;
  const int lane = tid & 63, wv = tid >> 6;
  const int r = lane & 15, g = lane >> 4;
  const long row = (long)blockIdx.x * 64 + wv * 16 + r;
  const float* xrow = X + row * (long)K;

  bf16x8 wreg[8];
  f32x4 xa[8], xb[8];

  // W slice load (global, linear-coalesced) and write (LDS, XOR-swizzled)
  auto WLOAD = [&](int s) {
    const int kc = s * 128;
    #pragma unroll
    for (int j = 0; j < 8; j++) {
      int i = tid + j * 256;                  // unit index, ordered (n, q)
      int n = i >> 4, q = i & 15;
      wreg[j] = *(const bf16x8*)(Wp + n * KP + kc + 8 * q);
    }
  };
  auto WWRITE = [&](int buf) {
    #pragma unroll
    for (int j = 0; j < 8; j++) {
      int i = tid + j * 256;
      int n = i >> 4, q = i & 15;
      *(bf16x8*)&Wl[buf][(q * 128 + (n ^ (q & 7))) * 8] = wreg[j];
    }
  };
  auto XLOAD = [&](int s, f32x4* xr) {
    const int kc = s * 128;
    #pragma unroll
    for (int c = 0; c < 4; c++) {
      int k0 = kc + 32 * c + 8 * g;
      xr[2*c]   = (k0     < K) ? *(const f32x4*)(xrow + k0)     : f32x4{0.f,0.f,0.f,0.f};
      xr[2*c+1] = (k0 + 4 < K) ? *(const f32x4*)(xrow + k0 + 4) : f32x4{0.f,0.f,0.f,0.f};
    }
  };

  // prologue: slice 0 in flight
  WLOAD(0); XLOAD(0, xa); WWRITE(0);
  f32x4 acc[8] = {};

  #pragma unroll 2
  for (int s = 0; s < S; s++) {
    __syncthreads();                          // W slice s staged; X slice s arrived
    if (s + 1 < S) { WLOAD(s + 1); XLOAD(s + 1, xb); WWRITE((s + 1) & 1); }
    bf16x8 af[4];
    #pragma unroll
    for (int c = 0; c < 4; c++) {
      #pragma unroll
      for (int j = 0; j < 4; j++) {
        af[c][j]     = (bf16)xa[2*c][j];
        af[c][4 + j] = (bf16)xa[2*c+1][j];
      }
    }
    #pragma unroll
    for (int c = 0; c < 4; c++) {
      const int q = 4 * c + g;
      const bf16* bp = &Wl[s & 1][(q * 128 + (r ^ (q & 7))) * 8];
      #pragma unroll
      for (int cc = 0; cc < 8; cc++) {
        bf16x8 bfr = *(const bf16x8*)(bp + cc * 128);
        acc[cc] = mfma16(af[c], bfr, acc[cc]);
      }
    }
    if (s + 1 < S) {
      #pragma unroll
      for (int k = 0; k < 8; k++) xa[k] = xb[k];
    }
  }

  const long rb = (long)blockIdx.x * 64 + wv * 16 + 4 * g;
  #pragma unroll
  for (int c = 0; c < 8; c++) {
    int col = 16 * c + r;
    float bb = bvec[col];
    #pragma unroll
    for (int j = 0; j < 4; j++) {
      float v = acc[c][j] + bb;
      v = v > 0.f ? v : 0.f;
      out[(rb + j) * 128 + col] = (bf16)v;
      out32[(rb + j) * 128 + col] = v;
    }
  }
}

// ---------------- generic 128x128 GEMM: C[M,128] = A[M,128] @ W.T (+epilogues) --------
// EPI: -1 = runtime per-descriptor epi (0 or 1)
//      0 = f32 out + bias (root GEMM -> root contribution)
//      1 = bf16 out, no bias (rel GEMM -> y)
//      2 = bf16 relu(acc + bias) (bt1; A fp32)
//      3 = acc + bias + res32 -> bf16 out AND f32 out2 (bt2 + residual -> x_base)
struct GDesc { const void* A; const bf16* W; const float* bias; const float* res32;
               void* out; void* out2; int nblk; int epi; };
struct GArgs { GDesc d[11]; };

template<int EPI, bool AF32, int NDESC>
__global__ __launch_bounds__(256) void gemm128_kernel(GArgs a)
{
  __shared__ bf16 Wl[16*128*8];  // 32KB; 16B-unit idx = q*128 + (n ^ (q&7))
  int b = blockIdx.x, di = 0;
  while (di + 1 < NDESC && b >= a.d[di].nblk) { b -= a.d[di].nblk; ++di; }
  const GDesc& D = a.d[di];
  const int tid = threadIdx.x;
  const int lane = tid & 63, wv = tid >> 6;
  const int r = lane & 15, g = lane >> 4;
  for (int i = tid; i < 2048; i += 256) {
    int q = i & 15, n = i >> 4;
    bf16x8 v = *(const bf16x8*)(D.W + n*128 + q*8);
    *(bf16x8*)&Wl[(q*128 + (n ^ (q & 7))) * 8] = v;
  }
  const long row = (long)b * 64 + wv * 16 + r;
  bf16x8 af[4];
  if constexpr (AF32) {
    const float* A = (const float*)D.A;
    #pragma unroll
    for (int kk = 0; kk < 4; kk++) {
      f32x4 a0 = *(const f32x4*)(A + row*128 + kk*32 + 8*g);
      f32x4 a1 = *(const f32x4*)(A + row*128 + kk*32 + 8*g + 4);
      #pragma unroll
      for (int j = 0; j < 4; j++) { af[kk][j] = (bf16)a0[j]; af[kk][4+j] = (bf16)a1[j]; }
    }
  } else {
    const bf16* A = (const bf16*)D.A;
    #pragma unroll
    for (int kk = 0; kk < 4; kk++)
      af[kk] = *(const bf16x8*)(A + row*128 + kk*32 + 8*g);
  }
  __syncthreads();
  f32x4 acc[8] = {};
  #pragma unroll
  for (int kk = 0; kk < 4; kk++) {
    int q = kk*4 + g;
    const bf16* bp = &Wl[(q*128 + (r ^ (q & 7))) * 8];
    #pragma unroll
    for (int c = 0; c < 8; c++) {
      bf16x8 bfr = *(const bf16x8*)(bp + c*128);
      acc[c] = mfma16(af[kk], bfr, acc[c]);
    }
  }
  const long rb = (long)b * 64 + wv * 16 + 4 * g;
  #pragma unroll
  for (int c = 0; c < 8; c++) {
    int col = 16*c + r;
    #pragma unroll
    for (int j = 0; j < 4; j++) {
      float v = acc[c][j];
      long oidx = (rb + j)*128 + col;
      if constexpr (EPI == -1) {
        if (D.epi == 0) ((float*)D.out)[oidx] = v + D.bias[col];
        else            ((bf16*)D.out)[oidx] = (bf16)v;
      } else if constexpr (EPI == 0) {
        ((float*)D.out)[oidx] = v + D.bias[col];
      } else if constexpr (EPI == 1) {
        ((bf16*)D.out)[oidx] = (bf16)v;
      } else if constexpr (EPI == 2) {
        v += D.bias[col];
        v = v > 0.f ? v : 0.f;
        ((bf16*)D.out)[oidx] = (bf16)v;
      } else {
        v += D.bias[col] + D.res32[oidx];
        ((bf16*)D.out)[oidx] = (bf16)v;
        ((float*)D.out2)[oidx] = v;
      }
    }
  }
}

// ---------------- CSR-gather aggregation (atomic-free) --------------------------------
// KIND 0 (base):  new_b[n] = root[n] + mean(y0) + mean(y1) + sum(y2) + sum(y4)  [fp32 out]
// KIND 1 (joint): x32 += relu(root[n] + sum(y3)+sum(y5)+sum(y7)); x16 = bf16(x32)
// KIND 2 (foot):  x32 += relu(root[n] + sum(y6)); x16 = bf16(x32)
struct AArgs { const bf16* y[4]; const float* root; float* o32; bf16* o16; };

template<int KIND>
__global__ __launch_bounds__(256) void agg_kernel(AArgs a,
    const int* __restrict__ rowptr, const int* __restrict__ perm)
{
  constexpr int NT = (KIND==0) ? 4 : ((KIND==1) ? 3 : 1);
  constexpr int OFFS[3][4] = {{0, 32768, 65536, 196608},
                              {98304, 229376, 360448, 0},
                              {327680, 0, 0, 0}};
  const int tid = threadIdx.x;
  const int lane = tid & 63, wv = tid >> 6;
  const int l8 = lane & 15, g = lane >> 4;
  const int node = blockIdx.x * 16 + wv * 4 + g;
  const long co = (long)node * 128 + l8 * 8;
  f32x4 a0 = *(const f32x4*)(a.root + co);
  f32x4 a1 = *(const f32x4*)(a.root + co + 4);
  #pragma unroll
  for (int ti = 0; ti < NT; ++ti) {
    const int slot = OFFS[KIND][ti] + node;
    int rp0 = rowptr[slot], rp1 = rowptr[slot + 1];
    float sc = 1.0f;
    if (KIND == 0 && ti < 2) {          // mean aggregation (gt, gs)
      int d = rp1 - rp0;
      sc = d > 0 ? 1.0f / (float)d : 1.0f;
    }
    const bf16* yb = a.y[ti];
    for (int e = rp0; e < rp1; ++e) {
      int src = perm[e];
      bf16x8 v = *(const bf16x8*)(yb + (long)src * 128 + l8 * 8);
      #pragma unroll
      for (int j = 0; j < 4; j++) {
        a0[j] += (float)v[j]   * sc;
        a1[j] += (float)v[4+j] * sc;
      }
    }
  }
  if constexpr (KIND == 0) {
    *(f32x4*)(a.o32 + co)     = a0;
    *(f32x4*)(a.o32 + co + 4) = a1;
  } else {
    f32x4 x0 = *(const f32x4*)(a.o32 + co);
    f32x4 x1 = *(const f32x4*)(a.o32 + co + 4);
    bf16x8 ov;
    #pragma unroll
    for (int j = 0; j < 4; j++) {
      float v0 = (a0[j] > 0.f ? a0[j] : 0.f) + x0[j];
      float v1 = (a1[j] > 0.f ? a1[j] : 0.f) + x1[j];
      x0[j] = v0; x1[j] = v1;
      ov[j] = (bf16)v0; ov[4+j] = (bf16)v1;
    }
    *(f32x4*)(a.o32 + co)     = x0;
    *(f32x4*)(a.o32 + co + 4) = x1;
    *(bf16x8*)(a.o16 + co)    = ov;
  }
}

// ---------------- decoder: out[8192,24] = xb32.view(8192,512) @ decW.T + b, * coeff ---
__global__ __launch_bounds__(256) void dec_kernel(const float* __restrict__ xb32,
    const float* __restrict__ W, const float* __restrict__ bvec,
    const float* __restrict__ clin, const float* __restrict__ cang,
    float* __restrict__ out)
{
  __shared__ float Wl[24*512];
  const int tid = threadIdx.x;
  for (int i = tid; i < 3072; i += 256)
    *(f32x4*)&Wl[i*4] = *(const f32x4*)(W + i*4);
  __syncthreads();
  const long row = (long)blockIdx.x * 256 + tid;
  float acc[24] = {};
  for (int k0 = 0; k0 < 512; k0 += 4) {
    f32x4 xv = *(const f32x4*)(xb32 + row*512 + k0);
    #pragma unroll
    for (int n = 0; n < 24; n++) {
      const float* wr = &Wl[n*512 + k0];
      float s = acc[n];
      #pragma unroll
      for (int j = 0; j < 4; j++) s += xv[j] * wr[j];
      acc[n] = s;
    }
  }
  #pragma unroll
  for (int n = 0; n < 24; n++) {
    int gq = n / 6, c = n - gq*6;
    float coef = (c < 3) ? clin[gq*3 + c] : cang[gq*3 + c - 3];
    out[row*24 + n] = (acc[n] + bvec[n]) * coef;
  }
}

// ===================================================================================
extern "C" void kernel_launch(void* const* d_in, const int* in_sizes, int n_in,
                              void* d_out, int out_size, void* d_ws, size_t ws_size,
                              hipStream_t stream)
{
  const float* x_base  = (const float*)d_in[0];
  const float* x_joint = (const float*)d_in[1];
  const float* x_foot  = (const float*)d_in[2];
  const float* eWb  = (const float*)d_in[3];
  const float* ebb  = (const float*)d_in[4];
  const float* eWj  = (const float*)d_in[5];
  const float* ebj  = (const float*)d_in[6];
  const float* eWf  = (const float*)d_in[7];
  const float* ebf  = (const float*)d_in[8];
  const float* Wrel  = (const float*)d_in[9];
  const float* Wroot = (const float*)d_in[10];
  const float* brel  = (const float*)d_in[11];
  const float* btW1  = (const float*)d_in[12];
  const float* btb1  = (const float*)d_in[13];
  const float* btW2  = (const float*)d_in[14];
  const float* btb2  = (const float*)d_in[15];
  const float* decW  = (const float*)d_in[16];
  const float* decb  = (const float*)d_in[17];
  const float* clin  = (const float*)d_in[18];
  const float* cang  = (const float*)d_in[19];
  const int* ei[8];
  for (int t = 0; t < 8; t++) ei[t] = (const int*)d_in[20 + t];

  char* p = (char*)d_ws;
  auto alloc = [&](size_t bytes) { char* r = p; p += (bytes + 255) & ~(size_t)255; return r; };
  bf16*  xb    = (bf16*) alloc((size_t)NBASE  * 128 * 2);
  bf16*  xj    = (bf16*) alloc((size_t)NJOINT * 128 * 2);
  bf16*  xf    = (bf16*) alloc((size_t)NFOOT  * 128 * 2);
  float* xb32  = (float*)alloc((size_t)NBASE  * 128 * 4);
  float* xj32  = (float*)alloc((size_t)NJOINT * 128 * 4);
  float* xf32  = (float*)alloc((size_t)NFOOT  * 128 * 4);
  float* new_b = (float*)alloc((size_t)NBASE  * 128 * 4);
  float* new_j = (float*)alloc((size_t)NJOINT * 128 * 4);
  float* new_f = (float*)alloc((size_t)NFOOT  * 128 * 4);
  const size_t ySrc[8] = {NBASE, NBASE, NBASE, NBASE, NJOINT, NJOINT, NJOINT, NFOOT};
  bf16* y[8];
  for (int t = 0; t < 8; t++) y[t] = (bf16*)alloc(ySrc[t] * 128 * 2);
  bf16*  hbt     = (bf16*) alloc((size_t)NBASE * 128 * 2);
  bf16*  Wrel_b  = (bf16*) alloc(4*8*16384*2);
  bf16*  Wroot_b = (bf16*) alloc(4*3*16384*2);
  bf16*  bt1_b   = (bf16*) alloc(16384*2);
  bf16*  bt2_b   = (bf16*) alloc(16384*2);
  float* bias_s  = (float*)alloc(4*3*128*4);
  bf16*  eWb_p   = (bf16*) alloc((size_t)128*1920*2);
  bf16*  eWj_p   = (bf16*) alloc((size_t)128*384*2);
  bf16*  eWf_p   = (bf16*) alloc((size_t)128*1024*2);
  int*   cnt     = (int*)  alloc((size_t)NSLOT*4);
  int*   rowptr  = (int*)  alloc((size_t)(NSLOT+1)*4);
  int*   cursor  = (int*)  alloc((size_t)NSLOT*4);
  int*   perm    = (int*)  alloc((size_t)NEDGE*4);
  int*   bsum    = (int*)  alloc((size_t)SCAN_BLOCKS*4);
  int*   bscan   = (int*)  alloc((size_t)SCAN_BLOCKS*4);
  (void)ws_size; (void)in_sizes; (void)n_in; (void)out_size;

  EArgs ea = { ei[0], ei[1], ei[2], ei[3], ei[4], ei[5], ei[6], ei[7] };

  prep_kernel<<<2048, 256, 0, stream>>>(Wrel, Wroot, brel, btW1, btW2,
                                        eWb, eWj, eWf,
                                        Wrel_b, Wroot_b, bias_s, bt1_b, bt2_b,
                                        eWb_p, eWj_p, eWf_p);
  zero_kernel<<<NSLOT/256, 256, 0, stream>>>(cnt);
  hist8_kernel<<<NEDGE/256, 256, 0, stream>>>(ea, cnt);
  scanA_kernel<<<SCAN_BLOCKS, 256, 0, stream>>>(cnt, bsum);
  scanB_kernel<<<1, 256, 0, stream>>>(bsum, bscan);
  scanC_kernel<<<SCAN_BLOCKS, 256, 0, stream>>>(cnt, bscan, rowptr, cursor);
  fill_kernel<<<NEDGE/256, 256, 0, stream>>>(ea, cursor, perm);

  enc2_kernel<1800,1920><<<512,  256, 0, stream>>>(x_base,  eWb_p, ebb, xb, xb32);
  enc2_kernel<300, 384> <<<1536, 256, 0, stream>>>(x_joint, eWj_p, ebj, xj, xj32);
  enc2_kernel<900, 1024><<<512,  256, 0, stream>>>(x_foot,  eWf_p, ebf, xf, xf32);

  const bf16* xsrc[8] = {xb, xb, xb, xb, xj, xj, xj, xf};
  const int nblkSrc[8] = {512, 512, 512, 512, 1536, 1536, 1536, 512};

  for (int l = 0; l < 4; l++) {
    // merged rel (epi 1) + root (epi 0) GEMMs: one 9728-block launch
    GArgs ra = {};
    for (int t = 0; t < 8; t++)
      ra.d[t] = GDesc{ xsrc[t], Wrel_b + (l*8 + t)*16384, nullptr, nullptr,
                       y[t], nullptr, nblkSrc[t], 1 };
    ra.d[8]  = GDesc{ xb, Wroot_b + (l*3 + 0)*16384, bias_s + (l*3 + 0)*128, nullptr,
                      new_b, nullptr, 512, 0 };
    ra.d[9]  = GDesc{ xj, Wroot_b + (l*3 + 1)*16384, bias_s + (l*3 + 1)*128, nullptr,
                      new_j, nullptr, 1536, 0 };
    ra.d[10] = GDesc{ xf, Wroot_b + (l*3 + 2)*16384, bias_s + (l*3 + 2)*128, nullptr,
                      new_f, nullptr, 512, 0 };
    gemm128_kernel<-1, false, 11><<<9728, 256, 0, stream>>>(ra);

    AArgs ab = { { y[0], y[1], y[2], y[4] }, new_b, new_b, nullptr };
    agg_kernel<0><<<NBASE/16, 256, 0, stream>>>(ab, rowptr, perm);
    AArgs aj = { { y[3], y[5], y[7], nullptr }, new_j, xj32, xj };
    agg_kernel<1><<<NJOINT/16, 256, 0, stream>>>(aj, rowptr, perm);
    AArgs af = { { y[6], nullptr, nullptr, nullptr }, new_f, xf32, xf };
    agg_kernel<2><<<NFOOT/16, 256, 0, stream>>>(af, rowptr, perm);

    GArgs b1 = {};
    b1.d[0] = GDesc{ new_b, bt1_b, btb1, nullptr, hbt, nullptr, 512, 2 };
    gemm128_kernel<2, true, 1><<<512, 256, 0, stream>>>(b1);

    GArgs b2a = {};
    b2a.d[0] = GDesc{ hbt, bt2_b, btb2, xb32, xb, xb32, 512, 3 };
    gemm128_kernel<3, false, 1><<<512, 256, 0, stream>>>(b2a);
  }

  dec_kernel<<<32, 256, 0, stream>>>(xb32, decW, decb, clin, cang, (float*)d_out);
}